// Round 9
// baseline (143.651 us; speedup 1.0000x reference)
//
#include <hip/hip_runtime.h>
#include <hip/hip_bf16.h>

typedef __bf16 bf16_t;
typedef __bf16 bf16x8 __attribute__((ext_vector_type(8)));
typedef float f32x4 __attribute__((ext_vector_type(4)));
typedef int i32x4 __attribute__((ext_vector_type(4)));

#define S_TOT 12288
#define F_IN 128
#define F_OUT 256
#define EPS 1e-5f

static __device__ __forceinline__ float silu_f(float v) {
  return v / (1.0f + __expf(-v));
}

static __device__ __forceinline__ void gll16(const bf16_t* g, bf16_t* l) {
  __builtin_amdgcn_global_load_lds(
      (const __attribute__((address_space(1))) void*)(const void*)g,
      (__attribute__((address_space(3))) void*)(void*)l, 16, 0, 0);
}

// ---------------- prep: pack weights (blocks 0..447) + GN1 stats (448..639) ----
// CHUNK-MAJOR pack: kcg = chunk*9 + tap (chunk = K32 slice, tap = neighbor k).
// Unit (kcg, cb): lane l holds B[f=32*chunk+8*(l>>4)+j of W_tap][o=16cb+(l&15)]
// at unit*1024B + l*16B. W1: 36 kcg; W2: 72 kcg; Wsk: 4 (chunk only).
__global__ void prep_kernel(const float* __restrict__ W1,
                            const float* __restrict__ W2,
                            const float* __restrict__ Wsk,
                            bf16_t* __restrict__ W1p,
                            bf16_t* __restrict__ W2p,
                            bf16_t* __restrict__ Wsp,
                            const float* __restrict__ x,
                            float* __restrict__ sum1, float* __restrict__ ss1) {
  __shared__ float gs[32], gq[32];
  if (blockIdx.x < 448) {
    int w = blockIdx.x * 4 + (threadIdx.x >> 6);
    int l = threadIdx.x & 63;
    int lo = l & 15, hi = l >> 4;
    const float* src;
    bf16_t* dst;
    int fbase, obase;
    if (w < 576) {
      int kcg = w >> 4, cb = w & 15;
      int tap = kcg % 9, chunk = kcg / 9;
      src = W1 + tap * 32768;
      dst = W1p + (size_t)w * 512;
      fbase = 32 * chunk + 8 * hi; obase = 16 * cb + lo;
    } else if (w < 1728) {
      int idx = w - 576;
      int kcg = idx >> 4, cb = idx & 15;
      int tap = kcg % 9, chunk = kcg / 9;
      src = W2 + tap * 65536;
      dst = W2p + (size_t)idx * 512;
      fbase = 32 * chunk + 8 * hi; obase = 16 * cb + lo;
    } else {
      int idx = w - 1728;
      int kc = idx >> 4, cb = idx & 15;
      src = Wsk;
      dst = Wsp + (size_t)idx * 512;
      fbase = 32 * kc + 8 * hi; obase = 16 * cb + lo;
    }
    bf16x8 v;
#pragma unroll
    for (int j = 0; j < 8; ++j)
      v[j] = (bf16_t)src[(fbase + j) * 256 + obase];
    *(bf16x8*)(dst + l * 8) = v;
  } else {
    int blk = blockIdx.x - 448;
    int vt = blk & 3;
    int s0 = (blk >> 2) * 256;
    int t = threadIdx.x;
    int col = t & 31, ro = t >> 5;
    float s_ = 0.f, q_ = 0.f;
    const f32x4* xp = (const f32x4*)(x + ((size_t)vt * S_TOT + s0) * F_IN);
#pragma unroll 4
    for (int it = 0; it < 32; ++it) {
      f32x4 v = xp[(size_t)(it * 8 + ro) * 32 + col];
      s_ += v[0] + v[1] + v[2] + v[3];
      q_ += v[0]*v[0] + v[1]*v[1] + v[2]*v[2] + v[3]*v[3];
    }
    if (t < 32) { gs[t] = 0.f; gq[t] = 0.f; }
    __syncthreads();
    atomicAdd(&gs[col], s_);
    atomicAdd(&gq[col], q_);
    __syncthreads();
    if (t < 32) {
      atomicAdd(&sum1[vt * 32 + t], gs[t]);
      atomicAdd(&ss1[vt * 32 + t], gq[t]);
    }
  }
}

// ---------------- apply GN1 (affine inline) + SiLU -> h1 ----------------
__global__ void apply_gn1(const float* __restrict__ x,
                          const float* __restrict__ sum1, const float* __restrict__ ss1,
                          const float* __restrict__ gs, const float* __restrict__ gb,
                          bf16_t* __restrict__ h1) {
  size_t base = ((size_t)blockIdx.x * 256 + threadIdx.x) * 8;
  int vt = (int)(base / ((size_t)S_TOT * F_IN));
  int c0 = (int)(base & (F_IN - 1));
  const f32x4* xp = (const f32x4*)(x + base);
  f32x4 v0 = xp[0], v1 = xp[1];
  float N = (float)(S_TOT * 4);
  bf16x8 o;
#pragma unroll
  for (int gi = 0; gi < 2; ++gi) {
    int g = (c0 >> 2) + gi;
    float mean = sum1[vt * 32 + g] / N;
    float var = ss1[vt * 32 + g] / N - mean * mean;
    float r = rsqrtf(var + EPS);
    f32x4 v = gi ? v1 : v0;
#pragma unroll
    for (int j = 0; j < 4; ++j) {
      int c = g * 4 + j;
      float a = r * gs[c];
      float b = gb[c] - mean * a;
      o[gi * 4 + j] = (bf16_t)silu_f(v[j] * a + b);
    }
  }
  *(bf16x8*)(h1 + base) = o;
}

// ---------------- apply GN2 (affine inline) + SiLU in place ----------------
__global__ void apply_gn2(bf16_t* __restrict__ h,
                          const float* __restrict__ sum_c, const float* __restrict__ ss_c,
                          const float* __restrict__ gs, const float* __restrict__ gb) {
  size_t base = ((size_t)blockIdx.x * 256 + threadIdx.x) * 8;
  int vt = (int)(base / ((size_t)S_TOT * F_OUT));
  int c0 = (int)(base & (F_OUT - 1));
  int g = c0 >> 3;
  bf16x8 v = *(const bf16x8*)(h + base);
  float sg = 0.f, qg = 0.f;
#pragma unroll
  for (int j = 0; j < 8; ++j) {
    sg += sum_c[vt * 256 + g * 8 + j];
    qg += ss_c[vt * 256 + g * 8 + j];
  }
  float N = (float)(S_TOT * 8);
  float mean = sg / N;
  float var = qg / N - mean * mean;
  float r = rsqrtf(var + EPS);
  bf16x8 o;
#pragma unroll
  for (int j = 0; j < 8; ++j) {
    int c = g * 8 + j;
    float a = r * gs[c];
    float b = gb[c] - mean * a;
    o[j] = (bf16_t)silu_f((float)v[j] * a + b);
  }
  *(bf16x8*)(h + base) = o;
}

// ---------------- unified gather-conv GEMM v9 ----------------
// = v8 (64 rows x 256 cols, 3 blocks/CU, A gll ring-3, B reg-dbuf, counted vmcnt)
// + K-LOOP PHASE ROTATION: block b starts its substage loop at
// off = (b>>8) * NMAIN/3 and wraps. The 3 co-resident blocks per CU run K-phases
// offset by 1/3 loop -> MFMA bursts / gather windows / barrier stalls interleave
// instead of colliding (breaks the phase-aligned convoy measured in R8).
// K-sum is order-independent -> rotation is correctness-neutral.
template<int RE, int NSUB, bool XSK>
__global__ __launch_bounds__(256, 3) void conv_kernel(
    const bf16_t* __restrict__ hsrc, const bf16_t* __restrict__ Wp,
    const bf16_t* __restrict__ Wsp, const float* __restrict__ x,
    const int* __restrict__ adjc, const float* __restrict__ bias,
    const float* __restrict__ biask, bf16_t* __restrict__ outb,
    float* __restrict__ outf, float* __restrict__ sum_c, float* __restrict__ ss_c) {
  const int tid = threadIdx.x;
  const int wv = tid >> 6, l = tid & 63;
  const int lo = l & 15, hi = l >> 4;
  const int nw = wv;

  int swz = ((blockIdx.x & 7) * 96) + (blockIdx.x >> 3);   // bijective: 768 = 8*96
  int vt = swz / 192;
  int rem = swz - vt * 192;
  int s0 = rem * 64;

  __shared__ int adjs[576];
  __shared__ bf16_t ab[3][2048];   // per buf: 64 rows x 32 elems (64B rows)

  for (int i = tid; i < 576; i += 256) adjs[i] = adjc[s0 * 9 + i];
  __syncthreads();

  const bf16_t* hb = hsrc + (size_t)vt * ((size_t)S_TOT * RE);
  constexpr int NMAIN = XSK ? (NSUB - 4) : NSUB;
  const int off = (blockIdx.x >> 8) * (NMAIN / 3);   // 0, NMAIN/3, 2*NMAIN/3
  auto phys = [&](int k) { int p = k + off; if (p >= NMAIN) p -= NMAIN; return p; };

  // A-stage for physical substage p (tap = p%9, chunk = p/9): 1 gll16 per wave.
  auto stageA = [&](int buf, int p) {
    int tap = p % 9, chunk = p / 9;
    int row = wv * 16 + (l >> 2);
    int segs = (l & 3) ^ ((row >> 1) & 3);
    const bf16_t* g = hb + (size_t)adjs[row * 9 + tap] * RE + chunk * 32 + segs * 8;
    gll16(g, &ab[buf][wv * 512]);
  };

  // B-stage: 4 asm global loads into regs, wave's 64-col strip of kcg = p.
  auto asmB = [&](i32x4* dst, const bf16_t* wsrc, int kcg) {
    const bf16_t* p = wsrc + (size_t)kcg * 8192 + nw * 2048 + l * 8;
    asm volatile(
        "global_load_dwordx4 %0, %4, off\n\t"
        "global_load_dwordx4 %1, %4, off offset:1024\n\t"
        "global_load_dwordx4 %2, %4, off offset:2048\n\t"
        "global_load_dwordx4 %3, %4, off offset:3072"
        : "=&v"(dst[0]), "=&v"(dst[1]), "=&v"(dst[2]), "=&v"(dst[3])
        : "v"(p));
  };

  // x-skip stage: f32 -> bf16 reg path into same swizzled A layout.
  auto stageX = [&](int buf, int sx) {
    int row = tid >> 2, q = tid & 3;
    const float* xr = x + ((size_t)vt * S_TOT + s0 + row) * F_IN + sx * 32 + q * 8;
    f32x4 xv0 = *(const f32x4*)(xr);
    f32x4 xv1 = *(const f32x4*)(xr + 4);
    bf16x8 w;
#pragma unroll
    for (int jj = 0; jj < 4; ++jj) {
      w[jj] = (bf16_t)xv0[jj];
      w[4 + jj] = (bf16_t)xv1[jj];
    }
    *(bf16x8*)(&ab[buf][row * 32 + ((q ^ ((row >> 1) & 3)) << 3)]) = w;
  };

  f32x4 acc[4][4] = {};
  auto compute = [&](int buf, const i32x4* bv) {
    bf16x8 afr[4];
#pragma unroll
    for (int mi = 0; mi < 4; ++mi) {
      int rr = mi * 16 + lo;
      afr[mi] = *(const bf16x8*)(&ab[buf][rr * 32 + ((hi ^ ((rr >> 1) & 3)) << 3)]);
    }
    __builtin_amdgcn_s_setprio(1);
#pragma unroll
    for (int mi = 0; mi < 4; ++mi)
#pragma unroll
      for (int ni = 0; ni < 4; ++ni)
        acc[mi][ni] = __builtin_amdgcn_mfma_f32_16x16x32_bf16(
            afr[mi], __builtin_bit_cast(bf16x8, bv[ni]), acc[mi][ni], 0, 0, 0);
    __builtin_amdgcn_s_setprio(0);
  };

  i32x4 b0[4], b1[4];
  // Prologue: in-flight at body top = A(s)[1], B(s)[4], A(s+1)[1].
  stageA(0, phys(0));
  asmB(b0, Wp, phys(0));
  stageA(1, phys(1));
  int bcur3 = 0, bstg3 = 2;

  for (int s = 0; s < NMAIN - 2; s += 2) {
    // even body: use b0 (phys(s)), load b1 (phys(s+1))
    asmB(b1, Wp, phys(s + 1));
    asm volatile("s_waitcnt vmcnt(5)" ::: "memory");  // A(s),B(s) landed
    __builtin_amdgcn_s_barrier();
    __builtin_amdgcn_sched_barrier(0);
    stageA(bstg3, phys(s + 2));
    compute(bcur3, b0);
    bcur3 = (bcur3 == 2) ? 0 : bcur3 + 1;
    bstg3 = (bstg3 == 2) ? 0 : bstg3 + 1;
    // odd body: use b1 (phys(s+1)), load b0 (phys(s+2))
    asmB(b0, Wp, phys(s + 2));
    asm volatile("s_waitcnt vmcnt(5)" ::: "memory");
    __builtin_amdgcn_s_barrier();
    __builtin_amdgcn_sched_barrier(0);
    stageA(bstg3, phys(s + 3));
    compute(bcur3, b1);
    bcur3 = (bcur3 == 2) ? 0 : bcur3 + 1;
    bstg3 = (bstg3 == 2) ? 0 : bstg3 + 1;
  }
  // body NMAIN-2 (use b0 = phys(NMAIN-2), load last B = phys(NMAIN-1); no stageA)
  asmB(b1, Wp, phys(NMAIN - 1));
  asm volatile("s_waitcnt vmcnt(5)" ::: "memory");
  __builtin_amdgcn_s_barrier();
  __builtin_amdgcn_sched_barrier(0);
  compute(bcur3, b0);
  bcur3 = (bcur3 == 2) ? 0 : bcur3 + 1;
  // body NMAIN-1 (use b1)
  asm volatile("s_waitcnt vmcnt(0)" ::: "memory");
  __builtin_amdgcn_s_barrier();
  __builtin_amdgcn_sched_barrier(0);
  compute(bcur3, b1);

  // ---- x-skip tail: 4 K32 substages from f32 x with W_skip (not rotated) ----
  if (XSK) {
#pragma unroll
    for (int sx = 0; sx < 4; ++sx) {
      int tb = sx & 1;
      __syncthreads();
      stageX(tb, sx);
      if (sx & 1) asmB(b1, Wsp, sx); else asmB(b0, Wsp, sx);
      asm volatile("s_waitcnt vmcnt(0)" ::: "memory");
      __syncthreads();
      __builtin_amdgcn_sched_barrier(0);
      compute(tb, (sx & 1) ? (const i32x4*)b1 : (const i32x4*)b0);
    }
  }

  if (!XSK) {
    bf16_t* ob = outb + ((size_t)vt * S_TOT + s0) * 256;
#pragma unroll
    for (int ni = 0; ni < 4; ++ni) {
      int o = nw * 64 + ni * 16 + lo;
      float bv = bias[o];
      float s_ = 0.f, q_ = 0.f;
#pragma unroll
      for (int mi = 0; mi < 4; ++mi)
#pragma unroll
        for (int r2 = 0; r2 < 4; ++r2) {
          int srow = mi * 16 + hi * 4 + r2;
          float v = acc[mi][ni][r2] + bv;
          ob[(size_t)srow * 256 + o] = (bf16_t)v;
          s_ += v; q_ += v * v;
        }
      s_ += __shfl_xor(s_, 16); s_ += __shfl_xor(s_, 32);
      q_ += __shfl_xor(q_, 16); q_ += __shfl_xor(q_, 32);
      if (hi == 0) {
        atomicAdd(&sum_c[vt * 256 + o], s_);
        atomicAdd(&ss_c[vt * 256 + o], q_);
      }
    }
  } else {
    float* of = outf + ((size_t)vt * S_TOT + s0) * 256;
#pragma unroll
    for (int ni = 0; ni < 4; ++ni) {
      int o = nw * 64 + ni * 16 + lo;
      float bv = bias[o] + biask[o];
#pragma unroll
      for (int mi = 0; mi < 4; ++mi)
#pragma unroll
        for (int r2 = 0; r2 < 4; ++r2) {
          int srow = mi * 16 + hi * 4 + r2;
          of[(size_t)srow * 256 + o] = acc[mi][ni][r2] + bv;
        }
    }
  }
}

extern "C" void kernel_launch(void* const* d_in, const int* in_sizes, int n_in,
                              void* d_out, int out_size, void* d_ws, size_t ws_size,
                              hipStream_t stream) {
  const float* x      = (const float*)d_in[0];
  const int*   adjc   = (const int*)d_in[1];
  const float* gn1_s  = (const float*)d_in[2];
  const float* gn1_b  = (const float*)d_in[3];
  const float* gn2_s  = (const float*)d_in[4];
  const float* gn2_b  = (const float*)d_in[5];
  const float* W_skip = (const float*)d_in[6];
  const float* b_skip = (const float*)d_in[7];
  const float* W1     = (const float*)d_in[8];
  const float* b1     = (const float*)d_in[9];
  const float* W2     = (const float*)d_in[10];
  const float* b2     = (const float*)d_in[11];
  float* out = (float*)d_out;

  float* sum1  = (float*)d_ws;           // 128
  float* ss1   = sum1 + 128;             // 128
  float* sum_c = ss1 + 128;              // 1024
  float* ss_c  = sum_c + 1024;           // 1024
  float* pad   = ss_c + 1024;            // 3072 (layout pad)
  bf16_t* W1p  = (bf16_t*)(pad + 3072);  // 294912
  bf16_t* W2p  = W1p + 294912;           // 589824
  bf16_t* Wsp  = W2p + 589824;           // 32768
  bf16_t* h1   = Wsp + 32768;            // 6291456
  bf16_t* out1 = h1 + 6291456;           // 12582912 (reused in place as h2)

  hipMemsetAsync(sum1, 0, (128 + 128 + 1024 + 1024) * sizeof(float), stream);
  prep_kernel<<<640, 256, 0, stream>>>(W1, W2, W_skip, W1p, W2p, Wsp, x, sum1, ss1);
  apply_gn1<<<3072, 256, 0, stream>>>(x, sum1, ss1, gn1_s, gn1_b, h1);
  conv_kernel<128, 36, false><<<768, 256, 0, stream>>>(
      h1, W1p, nullptr, nullptr, adjc, b1, nullptr, out1, nullptr, sum_c, ss_c);
  apply_gn2<<<6144, 256, 0, stream>>>(out1, sum_c, ss_c, gn2_s, gn2_b);
  conv_kernel<256, 76, true><<<768, 256, 0, stream>>>(
      out1, W2p, Wsp, x, adjc, b2, b_skip, nullptr, out, nullptr, nullptr);
}